// Round 1
// baseline (60.541 us; speedup 1.0000x reference)
//
#include <hip/hip_runtime.h>

#define EPS 1e-6f

// c2 = FIXED_T / (NUM_LEVELS-1) * log2(e) = 100/(15*ln2)
static constexpr float C2 = 9.617966939259756f;

#if __has_builtin(__builtin_amdgcn_exp2f)
__device__ __forceinline__ float fast_exp2(float x) { return __builtin_amdgcn_exp2f(x); }
#else
__device__ __forceinline__ float fast_exp2(float x) { return exp2f(x); }
#endif

#if __has_builtin(__builtin_amdgcn_rcpf)
__device__ __forceinline__ float fast_rcp(float x) { return __builtin_amdgcn_rcpf(x); }
#else
__device__ __forceinline__ float fast_rcp(float x) { return 1.0f / x; }
#endif

// deterministic block-wide sum for 256 threads (4 waves); red must have 4 floats per slot
__device__ __forceinline__ float block_sum_256(float v, float* red, int slot) {
    #pragma unroll
    for (int o = 32; o > 0; o >>= 1) v += __shfl_xor(v, o, 64);
    const int t = threadIdx.x;
    __syncthreads();  // protect any prior use of red
    if ((t & 63) == 0) red[slot * 4 + (t >> 6)] = v;
    __syncthreads();
    return red[slot * 4 + 0] + red[slot * 4 + 1] + red[slot * 4 + 2] + red[slot * 4 + 3];
}

__global__ __launch_bounds__(256) void bq_main_kernel(
    const float* __restrict__ weight,
    const float* __restrict__ w_min,
    const float* __restrict__ w_max,
    float* __restrict__ out,
    float* __restrict__ ent_partial)
{
    // one workgroup per 128x128 block; 1024 blocks (32x32)
    const int bid = blockIdx.x;
    const int br = bid >> 5;
    const int bc = bid & 31;
    const int t = threadIdx.x;       // 0..255
    const int c = t & 127;           // column within block
    const int h = t >> 7;            // 0: rows 0..63, 1: rows 64..127

    // ---- per-block scale params (reference semantics) ----
    const float wmn = w_min[bid];
    const float wmx = w_max[bid];
    const float lo = fminf(wmn, wmx - EPS);
    const float hi = fmaxf(wmx, lo + EPS);
    const float scale = hi - lo + EPS;
    const float s15 = 15.0f / scale;        // one precise division per thread
    const float dmm = hi - lo;

    // ---- constant table K[j] = 2^(C2*(7.5-j)) ; K2[j] == K[15-j] ----
    float K[16];
    #pragma unroll
    for (int j = 0; j < 16; ++j)
        K[j] = fast_exp2(C2 * (7.5f - (float)j));

    // per-thread bin accumulators: bin_mass contribution of this column-half
    float bin[16];
    #pragma unroll
    for (int j = 0; j < 16; ++j) bin[j] = 0.0f;

    const size_t base = (size_t)(br * 128 + h * 64) * 4096 + (size_t)(bc * 128 + c);
    const float* __restrict__ wp = weight + base;
    float* __restrict__ op = out + base;

    #pragma unroll 2
    for (int i = 0; i < 64; ++i) {
        const float w = wp[(size_t)i * 4096];
        // tp = 15*w_norm - 7.5
        const float tp = fmaf(w - lo, s15, -7.5f);
        const float x = C2 * tp;
        const float P = fast_exp2(x);
        const float Pi = fast_exp2(-x);

        float e[16];
        float S = 0.0f, W = 0.0f;
        #pragma unroll
        for (int j = 0; j < 16; ++j) {
            const float ej = fminf(P * K[j], Pi * K[15 - j]);
            e[j] = ej;
            S += ej;
            W = fmaf(ej, (float)j * (1.0f / 15.0f), W);
        }
        const float rS = fast_rcp(S);
        op[(size_t)i * 4096] = fmaf(W * rS, dmm, lo);
        #pragma unroll
        for (int j = 0; j < 16; ++j) bin[j] = fmaf(e[j], rS, bin[j]);
    }

    // ---- merge the two column halves (h==1 -> h==0) via LDS ----
    __shared__ float lds[128 * 17 + 8];
    float* red = lds + 128 * 17;

    if (h == 1) {
        #pragma unroll
        for (int j = 0; j < 16; ++j) lds[c * 17 + j] = bin[j];
    }
    __syncthreads();

    float s_local = 0.0f;
    if (h == 0) {
        #pragma unroll
        for (int j = 0; j < 16; ++j) {
            bin[j] += lds[c * 17 + j];
            s_local += bin[j];
        }
    }

    // total mass per block (should be ~16384, but compute actual like reference)
    const float B = block_sum_256(s_local, red, 0);
    const float invB = fast_rcp(B + EPS);

    float ent = 0.0f;
    if (h == 0) {
        #pragma unroll
        for (int j = 0; j < 16; ++j) {
            const float p = bin[j] * invB;
            ent = fmaf(p, __logf(p + EPS), ent);
        }
    }
    const float entB = block_sum_256(ent, red, 1);
    if (t == 0) ent_partial[bid] = -entB;
}

__global__ __launch_bounds__(256) void bq_ent_reduce(
    const float* __restrict__ part, float* __restrict__ out_ent)
{
    __shared__ float red[8];
    const int t = threadIdx.x;  // 256 threads, 1024 partials
    float v = part[t] + part[t + 256] + part[t + 512] + part[t + 768];
    #pragma unroll
    for (int o = 32; o > 0; o >>= 1) v += __shfl_xor(v, o, 64);
    if ((t & 63) == 0) red[t >> 6] = v;
    __syncthreads();
    if (t == 0) out_ent[0] = red[0] + red[1] + red[2] + red[3];
}

extern "C" void kernel_launch(void* const* d_in, const int* in_sizes, int n_in,
                              void* d_out, int out_size, void* d_ws, size_t ws_size,
                              hipStream_t stream) {
    const float* weight = (const float*)d_in[0];
    const float* wmin = (const float*)d_in[1];
    const float* wmax = (const float*)d_in[2];
    float* out = (float*)d_out;
    float* part = (float*)d_ws;  // 1024 floats of scratch

    bq_main_kernel<<<1024, 256, 0, stream>>>(weight, wmin, wmax, out, part);
    bq_ent_reduce<<<1, 256, 0, stream>>>(part, out + (out_size - 1));
}

// Round 2
// 54.224 us; speedup vs baseline: 1.1165x; 1.1165x over previous
//
#include <hip/hip_runtime.h>

#define EPS 1e-6f

// C2 = FIXED_T/(NUM_LEVELS-1) * log2(e) = 100/(15*ln2)
static constexpr float C2 = 9.617966939259756f;

#if __has_builtin(__builtin_amdgcn_exp2f)
__device__ __forceinline__ float fast_exp2(float x) { return __builtin_amdgcn_exp2f(x); }
#else
__device__ __forceinline__ float fast_exp2(float x) { return exp2f(x); }
#endif

#if __has_builtin(__builtin_amdgcn_rcpf)
__device__ __forceinline__ float fast_rcp(float x) { return __builtin_amdgcn_rcpf(x); }
#else
__device__ __forceinline__ float fast_rcp(float x) { return 1.0f / x; }
#endif

// deterministic block-wide sum for 512 threads (8 waves)
__device__ __forceinline__ float block_sum_512(float v, float* red, int slot) {
    #pragma unroll
    for (int o = 32; o > 0; o >>= 1) v += __shfl_xor(v, o, 64);
    const int t = threadIdx.x;
    __syncthreads();  // protect prior use of red
    if ((t & 63) == 0) red[slot * 8 + (t >> 6)] = v;
    __syncthreads();
    float s = 0.0f;
    #pragma unroll
    for (int wv = 0; wv < 8; ++wv) s += red[slot * 8 + wv];
    return s;
}

__global__ __launch_bounds__(512) void bq_main_kernel(
    const float* __restrict__ weight,
    const float* __restrict__ w_min,
    const float* __restrict__ w_max,
    float* __restrict__ out,
    float* __restrict__ ent_partial)
{
    // one 512-thread workgroup per 128x128 block; 1024 blocks (32x32)
    const int bid = blockIdx.x;
    const int br = bid >> 5;
    const int bc = bid & 31;
    const int t = threadIdx.x;       // 0..511
    const int c = t & 127;           // column within block
    const int q = t >> 7;            // row-quarter: rows [q*32, q*32+32)

    // ---- per-block scale params (reference semantics) ----
    const float wmn = w_min[bid];
    const float wmx = w_max[bid];
    const float lo = fminf(wmn, wmx - EPS);
    const float hi = fmaxf(wmx, lo + EPS);
    const float scale = hi - lo + EPS;
    const float s15 = 15.0f / scale;   // one precise division per thread
    const float dmm = hi - lo;

    // x = C2*(15*(w-lo)/scale - 7.5) = w*a + b
    const float a = C2 * s15;
    const float b = -C2 * fmaf(lo, s15, 7.5f);

    // ---- constant table K[j] = 2^(C2*(7.5-j)) ----
    float K[16];
    #pragma unroll
    for (int j = 0; j < 16; ++j)
        K[j] = fast_exp2(C2 * (7.5f - (float)j));

    float bin[16];
    #pragma unroll
    for (int j = 0; j < 16; ++j) bin[j] = 0.0f;

    const size_t base = (size_t)(br * 128 + q * 32) * 4096 + (size_t)(bc * 128 + c);
    const float* __restrict__ wp = weight + base;
    float* __restrict__ op = out + base;

    #pragma unroll 2
    for (int i = 0; i < 32; ++i) {
        const float w = wp[(size_t)i * 4096];
        const float x = fmaf(w, a, b);
        const float P = fast_exp2(x);
        const float Pi = fast_exp2(-x);

        float e[16];
        float S = 0.0f, W = 0.0f;
        #pragma unroll
        for (int j = 0; j < 16; ++j) {
            const float ej = fminf(P * K[j], Pi * K[15 - j]);
            e[j] = ej;
            S += ej;
            W = fmaf(ej, (float)j * (1.0f / 15.0f), W);
        }
        const float rS = fast_rcp(S);
        op[(size_t)i * 4096] = fmaf(W * rS, dmm, lo);
        #pragma unroll
        for (int j = 0; j < 16; ++j) bin[j] = fmaf(e[j], rS, bin[j]);
    }

    // ---- merge the four row-quarters' per-column bins via LDS ----
    // quarters 1..3 write; quarter 0 accumulates. Stride 17 avoids conflicts.
    __shared__ float lds[3 * 128 * 17 + 16];
    float* red = lds + 3 * 128 * 17;

    if (q > 0) {
        float* dst = lds + (q - 1) * (128 * 17) + c * 17;
        #pragma unroll
        for (int j = 0; j < 16; ++j) dst[j] = bin[j];
    }
    __syncthreads();

    float s_local = 0.0f;
    if (q == 0) {
        #pragma unroll
        for (int p = 0; p < 3; ++p) {
            const float* src = lds + p * (128 * 17) + c * 17;
            #pragma unroll
            for (int j = 0; j < 16; ++j) bin[j] += src[j];
        }
        #pragma unroll
        for (int j = 0; j < 16; ++j) s_local += bin[j];
    }

    const float B = block_sum_512(s_local, red, 0);
    const float invB = fast_rcp(B + EPS);

    float ent = 0.0f;
    if (q == 0) {
        #pragma unroll
        for (int j = 0; j < 16; ++j) {
            const float p = bin[j] * invB;
            ent = fmaf(p, __logf(p + EPS), ent);
        }
    }
    const float entB = block_sum_512(ent, red, 1);
    if (t == 0) ent_partial[bid] = -entB;
}

__global__ __launch_bounds__(256) void bq_ent_reduce(
    const float* __restrict__ part, float* __restrict__ out_ent)
{
    __shared__ float red[8];
    const int t = threadIdx.x;  // 256 threads, 1024 partials
    float v = part[t] + part[t + 256] + part[t + 512] + part[t + 768];
    #pragma unroll
    for (int o = 32; o > 0; o >>= 1) v += __shfl_xor(v, o, 64);
    if ((t & 63) == 0) red[t >> 6] = v;
    __syncthreads();
    if (t == 0) out_ent[0] = red[0] + red[1] + red[2] + red[3];
}

extern "C" void kernel_launch(void* const* d_in, const int* in_sizes, int n_in,
                              void* d_out, int out_size, void* d_ws, size_t ws_size,
                              hipStream_t stream) {
    const float* weight = (const float*)d_in[0];
    const float* wmin = (const float*)d_in[1];
    const float* wmax = (const float*)d_in[2];
    float* out = (float*)d_out;
    float* part = (float*)d_ws;  // 1024 floats of scratch

    bq_main_kernel<<<1024, 512, 0, stream>>>(weight, wmin, wmax, out, part);
    bq_ent_reduce<<<1, 256, 0, stream>>>(part, out + (out_size - 1));
}

// Round 3
// 35.787 us; speedup vs baseline: 1.6917x; 1.5152x over previous
//
#include <hip/hip_runtime.h>

#define EPS 1e-6f

// C2 = FIXED_T/(NUM_LEVELS-1) * log2(e) = 100/(15*ln2)
static constexpr float C2    = 9.617966939259756f;
static constexpr float C2_75 = 72.13475204444817f;  // C2*7.5

#if __has_builtin(__builtin_amdgcn_exp2f)
__device__ __forceinline__ float fast_exp2(float x) { return __builtin_amdgcn_exp2f(x); }
#else
__device__ __forceinline__ float fast_exp2(float x) { return exp2f(x); }
#endif

#if __has_builtin(__builtin_amdgcn_rcpf)
__device__ __forceinline__ float fast_rcp(float x) { return __builtin_amdgcn_rcpf(x); }
#else
__device__ __forceinline__ float fast_rcp(float x) { return 1.0f / x; }
#endif

// deterministic block-wide sum for 256 threads (4 waves)
__device__ __forceinline__ float block_sum_256(float v, float* red, int slot) {
    #pragma unroll
    for (int o = 32; o > 0; o >>= 1) v += __shfl_xor(v, o, 64);
    const int t = threadIdx.x;
    __syncthreads();  // protect prior use of red
    if ((t & 63) == 0) red[slot * 4 + (t >> 6)] = v;
    __syncthreads();
    return red[slot*4+0] + red[slot*4+1] + red[slot*4+2] + red[slot*4+3];
}

__global__ __launch_bounds__(256) void bq_main_kernel(
    const float* __restrict__ weight,
    const float* __restrict__ w_min,
    const float* __restrict__ w_max,
    float* __restrict__ out,
    float* __restrict__ ent_partial)
{
    // tables: tab[n] = {SA, SB, WA, WB};  uv[n][h][c] = {U, V} per column/half
    __shared__ float4 tab[16];
    __shared__ float2 uv[16][2][128];   // 32 KB

    const int bid = blockIdx.x;
    const int br = bid >> 5;
    const int bc = bid & 31;
    const int t = threadIdx.x;     // 0..255
    const int c = t & 127;         // column within block
    const int h = t >> 7;          // row half: rows [h*64, h*64+64)

    // zero own uv slots (no barrier needed: each thread owns its slots)
    #pragma unroll
    for (int n = 0; n < 16; ++n) uv[n][h][c] = make_float2(0.0f, 0.0f);

    // constant tables (block-independent geometric partial sums)
    if (t < 16) {
        const int n = t;
        float sa = 0.0f, sb = 0.0f, wa = 0.0f, wb = 0.0f;
        for (int j = 0; j < 16; ++j) {
            if (j <= n) {
                const float kk = fast_exp2(C2 * ((float)j - 7.5f));   // K[15-j]
                sa += kk; wa = fmaf(kk, (float)j * (1.0f/15.0f), wa);
            } else {
                const float kk = fast_exp2(C2 * (7.5f - (float)j));   // K[j]
                sb += kk; wb = fmaf(kk, (float)j * (1.0f/15.0f), wb);
            }
        }
        tab[n] = make_float4(sa, sb, wa, wb);
    }

    // per-block scale params (reference semantics)
    const float wmn = w_min[bid];
    const float wmx = w_max[bid];
    const float lo = fminf(wmn, wmx - EPS);
    const float hi = fmaxf(wmx, lo + EPS);
    const float scale = hi - lo + EPS;
    const float s15 = 15.0f / scale;
    const float dmm = hi - lo;
    const float tb0 = -lo * s15;     // t_hat = fmaf(w, s15, tb0)

    __syncthreads();

    const size_t base = (size_t)(br * 128 + h * 64) * 4096 + (size_t)(bc * 128 + c);
    const float* __restrict__ wp = weight + base;
    float* __restrict__ op = out + base;

    #pragma unroll 4
    for (int i = 0; i < 64; ++i) {
        const float w = wp[(size_t)i * 4096];
        const float th = fmaf(w, s15, tb0);                       // 15*w_norm
        const float nf = fminf(fmaxf(floorf(th), 0.0f), 15.0f);
        const int n = (int)nf;
        const float x = fmaf(th, C2, -C2_75);
        const float P  = fast_exp2(x);
        const float Pi = fast_exp2(-x);
        const float4 tb4 = tab[n];
        const float S = fmaf(Pi, tb4.x, P * tb4.y);
        const float W = fmaf(Pi, tb4.z, P * tb4.w);
        const float rS = fast_rcp(S);
        __builtin_nontemporal_store(fmaf(W * rS, dmm, lo), &op[(size_t)i * 4096]);
        float2 acc = uv[n][h][c];
        acc.x = fmaf(Pi, rS, acc.x);
        acc.y = fmaf(P,  rS, acc.y);
        uv[n][h][c] = acc;
    }

    __syncthreads();

    // epilogue: per-column bins from U/V histograms, then entropy
    float s_local = 0.0f, ent = 0.0f;
    float bin[16];
    if (h == 0) {
        float U[16], V[16];
        #pragma unroll
        for (int n = 0; n < 16; ++n) {
            const float2 a = uv[n][0][c];
            const float2 b = uv[n][1][c];
            U[n] = a.x + b.x;
            V[n] = a.y + b.y;
        }
        float suf = 0.0f;
        #pragma unroll
        for (int j = 15; j >= 0; --j) {
            suf += U[j];
            bin[j] = suf * fast_exp2(C2 * ((float)j - 7.5f));      // K[15-j]*SufU[j]
        }
        float pre = 0.0f;
        #pragma unroll
        for (int j = 0; j < 16; ++j) {
            bin[j] = fmaf(pre, fast_exp2(C2 * (7.5f - (float)j)), bin[j]);  // + K[j]*PreV[j]
            pre += V[j];
            s_local += bin[j];
        }
    }

    float* red = (float*)tab;   // tab no longer needed
    const float B = block_sum_256(s_local, red, 0);
    const float invB = fast_rcp(B + EPS);

    if (h == 0) {
        #pragma unroll
        for (int j = 0; j < 16; ++j) {
            const float p = bin[j] * invB;
            ent = fmaf(p, __logf(p + EPS), ent);
        }
    }
    const float entB = block_sum_256(ent, red, 1);
    if (t == 0) ent_partial[bid] = -entB;
}

__global__ __launch_bounds__(256) void bq_ent_reduce(
    const float* __restrict__ part, float* __restrict__ out_ent)
{
    __shared__ float red[8];
    const int t = threadIdx.x;  // 256 threads, 1024 partials
    float v = part[t] + part[t + 256] + part[t + 512] + part[t + 768];
    #pragma unroll
    for (int o = 32; o > 0; o >>= 1) v += __shfl_xor(v, o, 64);
    if ((t & 63) == 0) red[t >> 6] = v;
    __syncthreads();
    if (t == 0) out_ent[0] = red[0] + red[1] + red[2] + red[3];
}

extern "C" void kernel_launch(void* const* d_in, const int* in_sizes, int n_in,
                              void* d_out, int out_size, void* d_ws, size_t ws_size,
                              hipStream_t stream) {
    const float* weight = (const float*)d_in[0];
    const float* wmin = (const float*)d_in[1];
    const float* wmax = (const float*)d_in[2];
    float* out = (float*)d_out;
    float* part = (float*)d_ws;  // 1024 floats of scratch

    bq_main_kernel<<<1024, 256, 0, stream>>>(weight, wmin, wmax, out, part);
    bq_ent_reduce<<<1, 256, 0, stream>>>(part, out + (out_size - 1));
}